// Round 1
// baseline (755.069 us; speedup 1.0000x reference)
//
#include <hip/hip_runtime.h>
#include <cstdint>
#include <cstddef>

#define Bn 64
#define Sn 512
#define Hn 768
#define Tn 50

// ---------------- Kernel 1: emissions = hidden @ W + b ----------------
// Thread-per-row; hidden staged via LDS in h-chunks; W rows read uniformly
// (scalar-load path); acc[50] in VGPRs.
#define ROWS 256
#define HC 32

__global__ __launch_bounds__(256) void emissions_kernel(
    const float* __restrict__ hidden, const float* __restrict__ W,
    const float* __restrict__ bias, float* __restrict__ em) {
  __shared__ float lds[HC][ROWS];
  const int tid = threadIdx.x;
  const int row = blockIdx.x * ROWS + tid;
  float acc[Tn];
#pragma unroll
  for (int j = 0; j < Tn; ++j) acc[j] = bias[j];
  for (int hc = 0; hc < Hn; hc += HC) {
    __syncthreads();
    const float4* src =
        reinterpret_cast<const float4*>(hidden + (size_t)row * Hn + hc);
#pragma unroll
    for (int k = 0; k < HC / 4; ++k) {
      float4 v = src[k];
      lds[k * 4 + 0][tid] = v.x;
      lds[k * 4 + 1][tid] = v.y;
      lds[k * 4 + 2][tid] = v.z;
      lds[k * 4 + 3][tid] = v.w;
    }
    __syncthreads();
#pragma unroll 2
    for (int h = 0; h < HC; ++h) {
      float hv = lds[h][tid];
      const float* wrow = W + (size_t)(hc + h) * Tn;  // uniform -> s_load
#pragma unroll
      for (int j = 0; j < Tn; ++j) acc[j] = fmaf(hv, wrow[j], acc[j]);
    }
  }
  // em row is 200 B: 8-byte aligned -> float2 stores
  float2* dst = reinterpret_cast<float2*>(em + (size_t)row * Tn);
#pragma unroll
  for (int j = 0; j < Tn / 2; ++j) dst[j] = make_float2(acc[2 * j], acc[2 * j + 1]);
}

// ---------------- Kernel 2: CRF numerator + forward scan ----------------
// One wave (64 threads) per batch element. lane j < 50 owns state j.
// E[i][j] = exp(transitions[i][j]) held in 50 VGPRs per lane (constant
// across steps). Per step:
//   M = wavemax(alpha); p = exp(alpha - M)   (lane i holds p_i)
//   s_j = sum_i readlane(p,i) * E[i][j]      (50 FMAs, 4 accumulators)
//   alpha_j = em[t][j] + M + log(s_j)
// Early exit at len (mask is a prefix mask) — no per-step select needed.
__global__ __launch_bounds__(64) void crf_kernel(
    const float* __restrict__ em, const float* __restrict__ startT,
    const float* __restrict__ endT, const float* __restrict__ trans,
    const int* __restrict__ tag, const int* __restrict__ mask,
    float* __restrict__ out) {
  const int b = blockIdx.x;
  const int lane = threadIdx.x;
  const float* emb = em + (size_t)b * Sn * Tn;
  const int* tagb = tag + b * Sn;
  const int* maskb = mask + b * Sn;

  // ---- length = sum(mask) ----
  int len = 0;
  for (int t = lane; t < Sn; t += 64) len += maskb[t];
#pragma unroll
  for (int off = 1; off < 64; off <<= 1) len += __shfl_xor(len, off);

  // ---- numerator ----
  float np = 0.f;
  for (int t = 1 + lane; t < len; t += 64)
    np += trans[tagb[t - 1] * Tn + tagb[t]] + emb[(size_t)t * Tn + tagb[t]];
  if (lane == 0)
    np += startT[tagb[0]] + emb[tagb[0]] + endT[tagb[len - 1]];
#pragma unroll
  for (int off = 1; off < 64; off <<= 1) np += __shfl_xor(np, off);

  // ---- precompute E column j in registers ----
  const int jc = lane < Tn ? lane : 0;
  float e[Tn];
#pragma unroll
  for (int i = 0; i < Tn; ++i) e[i] = __expf(trans[i * Tn + jc]);

  // ---- forward scan ----
  float a = (lane < Tn) ? (startT[lane] + emb[lane]) : -INFINITY;

  float emj = emb[Tn + jc];  // prefetch t=1
  for (int t = 1; t < len; ++t) {
    float em_cur = emj;
    int tn = (t + 1 < Sn) ? t + 1 : Sn - 1;
    emj = emb[(size_t)tn * Tn + jc];  // prefetch next step (hidden under dot)

    float M = a;
#pragma unroll
    for (int off = 1; off < 64; off <<= 1) M = fmaxf(M, __shfl_xor(M, off));
    float p = __expf(a - M);  // lanes >= 50: exp(-inf) = 0 (never read anyway)

    float s0 = 0.f, s1 = 0.f, s2 = 0.f, s3 = 0.f;
#pragma unroll
    for (int i = 0; i < 48; i += 4) {
      s0 = fmaf(__shfl(p, i + 0), e[i + 0], s0);
      s1 = fmaf(__shfl(p, i + 1), e[i + 1], s1);
      s2 = fmaf(__shfl(p, i + 2), e[i + 2], s2);
      s3 = fmaf(__shfl(p, i + 3), e[i + 3], s3);
    }
    s0 = fmaf(__shfl(p, 48), e[48], s0);
    s1 = fmaf(__shfl(p, 49), e[49], s1);
    float s = (s0 + s1) + (s2 + s3);

    float anew = em_cur + M + __logf(s);
    a = (lane < Tn) ? anew : -INFINITY;
  }

  // ---- denominator = lse(alpha + end) ----
  float dv = (lane < Tn) ? (a + endT[lane]) : -INFINITY;
  float M2 = dv;
#pragma unroll
  for (int off = 1; off < 64; off <<= 1) M2 = fmaxf(M2, __shfl_xor(M2, off));
  float sd = __expf(dv - M2);
#pragma unroll
  for (int off = 1; off < 64; off <<= 1) sd += __shfl_xor(sd, off);

  if (lane == 0) out[b] = (M2 + __logf(sd)) - np;
}

extern "C" void kernel_launch(void* const* d_in, const int* in_sizes, int n_in,
                              void* d_out, int out_size, void* d_ws,
                              size_t ws_size, hipStream_t stream) {
  const float* hidden = (const float*)d_in[0];
  const float* W = (const float*)d_in[1];
  const float* bias = (const float*)d_in[2];
  const float* startT = (const float*)d_in[3];
  const float* endT = (const float*)d_in[4];
  const float* trans = (const float*)d_in[5];
  const int* tag = (const int*)d_in[6];
  const int* mask = (const int*)d_in[7];
  float* out = (float*)d_out;
  float* em = (float*)d_ws;  // 64*512*50 f32 = 6.55 MB

  emissions_kernel<<<(Bn * Sn) / ROWS, 256, 0, stream>>>(hidden, W, bias, em);
  crf_kernel<<<Bn, 64, 0, stream>>>(em, startT, endT, trans, tag, mask, out);
}

// Round 2
// 235.896 us; speedup vs baseline: 3.2009x; 3.2009x over previous
//
#include <hip/hip_runtime.h>
#include <cstdint>
#include <cstddef>

#define Bn 64
#define Sn 512
#define Hn 768
#define Tn 50

__device__ __forceinline__ float rdlane(float v, int i) {
  return __uint_as_float(__builtin_amdgcn_readlane(__float_as_uint(v), i));
}

// ---------------- Kernel 1: emissions = hidden @ W + b ----------------
// Block = 256 threads = 4 waves; block covers 64 rows; wave w covers all 64
// rows for a 13-tag segment j0 = {0,13,26,37} (cols 37,38 duplicated, same
// value). Hidden tile staged in LDS (coalesced 128B segments); W read via
// wave-uniform scalar loads; 13 accumulators in VGPRs.
#define RB 64
#define HC 32

__global__ __launch_bounds__(256) void emissions_kernel(
    const float* __restrict__ hidden, const float* __restrict__ W,
    const float* __restrict__ bias, float* __restrict__ em) {
  __shared__ float lds_h[RB][HC + 1];
  const int tid = threadIdx.x;
  const int lane = tid & 63;
  const int wv = tid >> 6;
  const int row0 = blockIdx.x * RB;
  const int j0 = __builtin_amdgcn_readfirstlane(wv * 13 - (wv == 3 ? 2 : 0));

  float acc[13];
#pragma unroll
  for (int jj = 0; jj < 13; ++jj) acc[jj] = bias[j0 + jj];

  for (int hc = 0; hc < Hn; hc += HC) {
    __syncthreads();
    // stage 64x32 tile: 512 float4 loads, 2 per thread, coalesced
#pragma unroll
    for (int k = 0; k < 2; ++k) {
      int idx = tid + k * 256;
      int r = idx >> 3, p = idx & 7;
      const float4 v = *reinterpret_cast<const float4*>(
          hidden + (size_t)(row0 + r) * Hn + hc + p * 4);
      lds_h[r][p * 4 + 0] = v.x;
      lds_h[r][p * 4 + 1] = v.y;
      lds_h[r][p * 4 + 2] = v.z;
      lds_h[r][p * 4 + 3] = v.w;
    }
    __syncthreads();
#pragma unroll 4
    for (int h = 0; h < HC; ++h) {
      const float hv = lds_h[lane][h];
      const float* wrow = W + (size_t)(hc + h) * Tn + j0;  // uniform -> s_load
#pragma unroll
      for (int jj = 0; jj < 13; ++jj) acc[jj] = fmaf(hv, wrow[jj], acc[jj]);
    }
  }
  float* dst = em + (size_t)(row0 + lane) * Tn + j0;
#pragma unroll
  for (int jj = 0; jj < 13; ++jj) dst[jj] = acc[jj];
}

// ---------------- Kernel 2: CRF numerator + forward scan ----------------
// One wave per batch. Lane j<50 owns state j. Linear-space recurrence:
//   q_j = exp(alpha_j - C), C wave-uniform.
//   per step: s_j = sum_i q_i * E[i][j]  (readlane broadcast + SGPR-fmac)
//             q'_j = exp(em_t[j]) * s_j   (exp precomputed off critical path)
//   renorm every 8 steps: M = wavemax(q); r = rcp(M); q *= r; C -= log(r).
__global__ __launch_bounds__(64) void crf_kernel(
    const float* __restrict__ em, const float* __restrict__ startT,
    const float* __restrict__ endT, const float* __restrict__ trans,
    const int* __restrict__ tag, const int* __restrict__ mask,
    float* __restrict__ out) {
  const int b = blockIdx.x;
  const int lane = threadIdx.x;
  const float* emb = em + (size_t)b * Sn * Tn;
  const int* tagb = tag + b * Sn;
  const int* maskb = mask + b * Sn;

  // ---- length ----
  int len = 0;
  for (int t = lane; t < Sn; t += 64) len += maskb[t];
#pragma unroll
  for (int off = 1; off < 64; off <<= 1) len += __shfl_xor(len, off);

  // ---- numerator ----
  float np = 0.f;
  for (int t = 1 + lane; t < len; t += 64)
    np += trans[tagb[t - 1] * Tn + tagb[t]] + emb[(size_t)t * Tn + tagb[t]];
  if (lane == 0)
    np += startT[tagb[0]] + emb[tagb[0]] + endT[tagb[len - 1]];
#pragma unroll
  for (int off = 1; off < 64; off <<= 1) np += __shfl_xor(np, off);

  // ---- E column j in registers ----
  const int jc = lane < Tn ? lane : 0;
  const bool live = lane < Tn;
  float e[Tn];
#pragma unroll
  for (int i = 0; i < Tn; ++i) e[i] = __expf(trans[i * Tn + jc]);

  // ---- scan (linear space) ----
  float C = 0.f;
  float q = live ? __expf(startT[jc] + emb[jc]) : 0.f;

  // em prefetch pipeline: ld1 holds em[t+1], ee holds exp(em[t]) (masked)
  float ld1 = emb[(Sn > 1 ? 1 : 0) * Tn + jc];   // em[1]
  float ee = live ? __expf(ld1) : 0.f;           // eem for t=1
  ld1 = emb[2 * Tn + jc];                        // em[2]

  for (int t = 1; t < len; ++t) {
    const float ee_cur = ee;
    const int tnx = (t + 2 < Sn) ? t + 2 : Sn - 1;
    const float ld_next = emb[(size_t)tnx * Tn + jc];  // em[t+2]
    ee = live ? __expf(ld1) : 0.f;                     // eem for t+1
    ld1 = ld_next;

    float s0 = 0.f, s1 = 0.f, s2 = 0.f, s3 = 0.f;
#pragma unroll
    for (int i = 0; i < 48; i += 4) {
      s0 = fmaf(rdlane(q, i + 0), e[i + 0], s0);
      s1 = fmaf(rdlane(q, i + 1), e[i + 1], s1);
      s2 = fmaf(rdlane(q, i + 2), e[i + 2], s2);
      s3 = fmaf(rdlane(q, i + 3), e[i + 3], s3);
    }
    s0 = fmaf(rdlane(q, 48), e[48], s0);
    s1 = fmaf(rdlane(q, 49), e[49], s1);
    q = ee_cur * ((s0 + s1) + (s2 + s3));

    if ((t & 7) == 0) {  // renorm: bounded to < e^60 between renorms
      float M = q;
#pragma unroll
      for (int off = 1; off < 64; off <<= 1) M = fmaxf(M, __shfl_xor(M, off));
      const float r = __builtin_amdgcn_rcpf(M);
      q *= r;
      C -= __logf(r);
    }
  }

  // ---- denominator ----
  float dv = live ? q * __expf(endT[jc]) : 0.f;
#pragma unroll
  for (int off = 1; off < 64; off <<= 1) dv += __shfl_xor(dv, off);

  if (lane == 0) out[b] = (C + __logf(dv)) - np;
}

extern "C" void kernel_launch(void* const* d_in, const int* in_sizes, int n_in,
                              void* d_out, int out_size, void* d_ws,
                              size_t ws_size, hipStream_t stream) {
  const float* hidden = (const float*)d_in[0];
  const float* W = (const float*)d_in[1];
  const float* bias = (const float*)d_in[2];
  const float* startT = (const float*)d_in[3];
  const float* endT = (const float*)d_in[4];
  const float* trans = (const float*)d_in[5];
  const int* tag = (const int*)d_in[6];
  const int* mask = (const int*)d_in[7];
  float* out = (float*)d_out;
  float* em = (float*)d_ws;  // 64*512*50 f32 = 6.55 MB

  emissions_kernel<<<(Bn * Sn) / RB, 256, 0, stream>>>(hidden, W, bias, em);
  crf_kernel<<<Bn, 64, 0, stream>>>(em, startT, endT, trans, tag, mask, out);
}

// Round 3
// 160.579 us; speedup vs baseline: 4.7022x; 1.4690x over previous
//
#include <hip/hip_runtime.h>
#include <cstdint>
#include <cstddef>

#define Bn 64
#define Sn 512
#define Hn 768
#define Tn 50

typedef short short8 __attribute__((ext_vector_type(8)));
typedef float floatx4 __attribute__((ext_vector_type(4)));

__device__ __forceinline__ uint32_t rne_bf16(float x) {
  uint32_t u = __float_as_uint(x);
  return (u + 0x7FFFu + ((u >> 16) & 1u)) >> 16;
}
__device__ __forceinline__ uint32_t pack2(float a, float b) {
  return rne_bf16(a) | (rne_bf16(b) << 16);
}
__device__ __forceinline__ float rdlane(float v, int i) {
  return __uint_as_float(__builtin_amdgcn_readlane(__float_as_uint(v), i));
}

// ---------------- Kernel 0: prep — lengths + W fragment pack ----------------
// blocks 0..63: len[b] = sum(mask[b]). blocks 64..87: Wfrag bf16 pack, padded
// to N=64: Wfrag[(ks*4+nt)*64 + lane] = 8 bf16, elem j = W[ks*32+(l>>4)*8+j][nt*16+(l&15)].
__global__ __launch_bounds__(256) void prep_kernel(
    const float* __restrict__ W, const int* __restrict__ mask,
    uint32_t* __restrict__ wfrag, int* __restrict__ lenbuf) {
  const int blk = blockIdx.x;
  const int tid = threadIdx.x;
  if (blk < 64) {
    if (tid < 64) {
      int s = 0;
      for (int t = tid; t < Sn; t += 64) s += mask[blk * Sn + t];
#pragma unroll
      for (int off = 1; off < 64; off <<= 1) s += __shfl_xor(s, off);
      if (tid == 0) lenbuf[blk] = s;
    }
    return;
  }
  const int gid = (blk - 64) * 256 + tid;  // [0, 6144)
  const int f = gid >> 6;                  // 0..95
  const int l = gid & 63;
  const int ks = f >> 2, nt = f & 3;
  const int col = nt * 16 + (l & 15);
  const int k0 = ks * 32 + (l >> 4) * 8;
  float v[8];
#pragma unroll
  for (int j = 0; j < 8; ++j)
    v[j] = (col < Tn) ? W[(size_t)(k0 + j) * Tn + col] : 0.f;
  uint4 d;
  d.x = pack2(v[0], v[1]);
  d.y = pack2(v[2], v[3]);
  d.z = pack2(v[4], v[5]);
  d.w = pack2(v[6], v[7]);
  ((uint4*)wfrag)[gid] = d;
}

// ---------------- Kernel 1: emissions via MFMA ----------------
// Block = 4 waves, 64 rows (batch bb, s-chunk c). Wave w owns rows
// [w*16, w*16+16) x all 64 (padded) tags. Wave-private LDS A staging
// (no __syncthreads), XOR-swizzled for conflict-free ds_read_b128.
// B fragments direct from pre-packed global (L2-hot). Reg-prefetch of
// next K-chunk overlaps HBM latency with compute.
#define BK 64

__global__ __launch_bounds__(256) void emissions_kernel(
    const float* __restrict__ hidden, const uint32_t* __restrict__ wfrag,
    const float* __restrict__ bias, const int* __restrict__ lenbuf,
    float* __restrict__ em) {
  const int blk = blockIdx.x;
  const int bb = blk >> 3, c = blk & 7;
  if (c * 64 >= lenbuf[bb]) return;  // rows never read by CRF
  const int tid = threadIdx.x;
  const int lane = tid & 63;
  const int w = tid >> 6;
  const int g = lane >> 4;   // 0..3
  const int li = lane & 15;  // 0..15
  const int row0 = blk * 64;
  __shared__ char lds_raw[64 * 128];  // [64 rows][64 bf16], swizzled

  floatx4 acc[4];
#pragma unroll
  for (int nt = 0; nt < 4; ++nt) acc[nt] = (floatx4)0.f;

  const float* hbase = hidden + (size_t)row0 * Hn;
  const short8* wf = (const short8*)wfrag;

  // staging map: load k -> row_local = w*16 + 4k + g, float4 index li
  float4 pf[4];
#pragma unroll
  for (int k = 0; k < 4; ++k)
    pf[k] = *(const float4*)(hbase + (size_t)(w * 16 + 4 * k + g) * Hn + li * 4);

  for (int ch = 0; ch < Hn / BK; ++ch) {
    // write prefetched chunk to LDS (bf16, swizzled)
#pragma unroll
    for (int k = 0; k < 4; ++k) {
      const int r = w * 16 + 4 * k + g;
      const uint32_t b0 = pack2(pf[k].x, pf[k].y);
      const uint32_t b1 = pack2(pf[k].z, pf[k].w);
      const int byteoff = r * 128 + ((li * 8) ^ ((r & 7) << 4));
      *(uint2*)(lds_raw + byteoff) = make_uint2(b0, b1);
    }
    // issue next chunk's global loads early (hide HBM under compute)
    if (ch + 1 < Hn / BK) {
      const int kc = (ch + 1) * BK;
#pragma unroll
      for (int k = 0; k < 4; ++k)
        pf[k] = *(const float4*)(hbase + (size_t)(w * 16 + 4 * k + g) * Hn + kc +
                                 li * 4);
    }
    asm volatile("s_waitcnt lgkmcnt(0)" ::: "memory");
#pragma unroll
    for (int ks = 0; ks < 2; ++ks) {
      const int r = w * 16 + li;
      const int kb = ks * 64 + g * 16;
      const short8 af =
          *(const short8*)(lds_raw + r * 128 + (kb ^ ((r & 7) << 4)));
      const int ksg = ch * 2 + ks;
#pragma unroll
      for (int nt = 0; nt < 4; ++nt) {
        const short8 bf = wf[(ksg * 4 + nt) * 64 + lane];
        acc[nt] =
            __builtin_amdgcn_mfma_f32_16x16x32_bf16(af, bf, acc[nt], 0, 0, 0);
      }
    }
  }
  // epilogue: C layout col=lane&15, row=(lane>>4)*4+reg
#pragma unroll
  for (int nt = 0; nt < 4; ++nt) {
    const int col = nt * 16 + li;
    if (col < Tn) {
      const float bs = bias[col];
#pragma unroll
      for (int r = 0; r < 4; ++r) {
        const int row = row0 + w * 16 + g * 4 + r;
        em[(size_t)row * Tn + col] = acc[nt][r] + bs;
      }
    }
  }
}

// ---------------- Kernel 2: CRF numerator + forward scan ----------------
// (unchanged from round 2 — linear-space recurrence, readlane broadcasts)
__global__ __launch_bounds__(64) void crf_kernel(
    const float* __restrict__ em, const float* __restrict__ startT,
    const float* __restrict__ endT, const float* __restrict__ trans,
    const int* __restrict__ tag, const int* __restrict__ mask,
    float* __restrict__ out) {
  const int b = blockIdx.x;
  const int lane = threadIdx.x;
  const float* emb = em + (size_t)b * Sn * Tn;
  const int* tagb = tag + b * Sn;
  const int* maskb = mask + b * Sn;

  int len = 0;
  for (int t = lane; t < Sn; t += 64) len += maskb[t];
#pragma unroll
  for (int off = 1; off < 64; off <<= 1) len += __shfl_xor(len, off);

  float np = 0.f;
  for (int t = 1 + lane; t < len; t += 64)
    np += trans[tagb[t - 1] * Tn + tagb[t]] + emb[(size_t)t * Tn + tagb[t]];
  if (lane == 0)
    np += startT[tagb[0]] + emb[tagb[0]] + endT[tagb[len - 1]];
#pragma unroll
  for (int off = 1; off < 64; off <<= 1) np += __shfl_xor(np, off);

  const int jc = lane < Tn ? lane : 0;
  const bool live = lane < Tn;
  float e[Tn];
#pragma unroll
  for (int i = 0; i < Tn; ++i) e[i] = __expf(trans[i * Tn + jc]);

  float C = 0.f;
  float q = live ? __expf(startT[jc] + emb[jc]) : 0.f;

  float ld1 = emb[Tn + jc];             // em[1]
  float ee = live ? __expf(ld1) : 0.f;  // eem for t=1
  ld1 = emb[2 * Tn + jc];               // em[2]

  for (int t = 1; t < len; ++t) {
    const float ee_cur = ee;
    const int tnx = (t + 2 < Sn) ? t + 2 : Sn - 1;
    const float ld_next = emb[(size_t)tnx * Tn + jc];
    ee = live ? __expf(ld1) : 0.f;
    ld1 = ld_next;

    float s0 = 0.f, s1 = 0.f, s2 = 0.f, s3 = 0.f;
#pragma unroll
    for (int i = 0; i < 48; i += 4) {
      s0 = fmaf(rdlane(q, i + 0), e[i + 0], s0);
      s1 = fmaf(rdlane(q, i + 1), e[i + 1], s1);
      s2 = fmaf(rdlane(q, i + 2), e[i + 2], s2);
      s3 = fmaf(rdlane(q, i + 3), e[i + 3], s3);
    }
    s0 = fmaf(rdlane(q, 48), e[48], s0);
    s1 = fmaf(rdlane(q, 49), e[49], s1);
    q = ee_cur * ((s0 + s1) + (s2 + s3));

    if ((t & 7) == 0) {
      float M = q;
#pragma unroll
      for (int off = 1; off < 64; off <<= 1) M = fmaxf(M, __shfl_xor(M, off));
      const float r = __builtin_amdgcn_rcpf(M);
      q *= r;
      C -= __logf(r);
    }
  }

  float dv = live ? q * __expf(endT[jc]) : 0.f;
#pragma unroll
  for (int off = 1; off < 64; off <<= 1) dv += __shfl_xor(dv, off);

  if (lane == 0) out[b] = (C + __logf(dv)) - np;
}

extern "C" void kernel_launch(void* const* d_in, const int* in_sizes, int n_in,
                              void* d_out, int out_size, void* d_ws,
                              size_t ws_size, hipStream_t stream) {
  const float* hidden = (const float*)d_in[0];
  const float* W = (const float*)d_in[1];
  const float* bias = (const float*)d_in[2];
  const float* startT = (const float*)d_in[3];
  const float* endT = (const float*)d_in[4];
  const float* trans = (const float*)d_in[5];
  const int* tag = (const int*)d_in[6];
  const int* mask = (const int*)d_in[7];
  float* out = (float*)d_out;

  // ws layout: em (6,553,600 B) | wfrag (98,304 B) | lenbuf (256 B)
  char* ws = (char*)d_ws;
  float* em = (float*)ws;
  uint32_t* wfrag = (uint32_t*)(ws + (size_t)Bn * Sn * Tn * 4);
  int* lenbuf = (int*)(ws + (size_t)Bn * Sn * Tn * 4 + 96 * 64 * 16);

  prep_kernel<<<88, 256, 0, stream>>>(W, mask, wfrag, lenbuf);
  emissions_kernel<<<(Bn * Sn) / 64, 256, 0, stream>>>(hidden, wfrag, bias,
                                                       lenbuf, em);
  crf_kernel<<<Bn, 64, 0, stream>>>(em, startT, endT, trans, tag, mask, out);
}

// Round 4
// 62.935 us; speedup vs baseline: 11.9976x; 2.5515x over previous
//
#include <hip/hip_runtime.h>
#include <cstdint>
#include <cstddef>

#define Bn 64
#define Sn 512
#define Hn 768
#define Tn 50
#define CH 32   // scan chunk length (steps)
#define NCH 16  // max chunks per sequence = ceil((Sn-1)/CH)

typedef short short8 __attribute__((ext_vector_type(8)));
typedef float floatx4 __attribute__((ext_vector_type(4)));

__device__ __forceinline__ uint32_t rne_bf16(float x) {
  uint32_t u = __float_as_uint(x);
  return (u + 0x7FFFu + ((u >> 16) & 1u)) >> 16;
}
__device__ __forceinline__ uint32_t pack2(float a, float b) {
  return rne_bf16(a) | (rne_bf16(b) << 16);
}
__device__ __forceinline__ float rdlane(float v, int i) {
  return __uint_as_float(__builtin_amdgcn_readlane(__float_as_uint(v), i));
}

// ---------------- Kernel 0: prep — lengths + W fragment pack ----------------
__global__ __launch_bounds__(256) void prep_kernel(
    const float* __restrict__ W, const int* __restrict__ mask,
    uint32_t* __restrict__ wfrag, int* __restrict__ lenbuf) {
  const int blk = blockIdx.x;
  const int tid = threadIdx.x;
  if (blk < 64) {
    if (tid < 64) {
      int s = 0;
      for (int t = tid; t < Sn; t += 64) s += mask[blk * Sn + t];
#pragma unroll
      for (int off = 1; off < 64; off <<= 1) s += __shfl_xor(s, off);
      if (tid == 0) lenbuf[blk] = s;
    }
    return;
  }
  const int gid = (blk - 64) * 256 + tid;  // [0, 6144)
  const int f = gid >> 6;                  // 0..95
  const int l = gid & 63;
  const int ks = f >> 2, nt = f & 3;
  const int col = nt * 16 + (l & 15);
  const int k0 = ks * 32 + (l >> 4) * 8;
  float v[8];
#pragma unroll
  for (int j = 0; j < 8; ++j)
    v[j] = (col < Tn) ? W[(size_t)(k0 + j) * Tn + col] : 0.f;
  uint4 d;
  d.x = pack2(v[0], v[1]);
  d.y = pack2(v[2], v[3]);
  d.z = pack2(v[4], v[5]);
  d.w = pack2(v[6], v[7]);
  ((uint4*)wfrag)[gid] = d;
}

// ---------------- Kernel 1: emissions via MFMA (unchanged r3) ----------------
#define BK 64
__global__ __launch_bounds__(256) void emissions_kernel(
    const float* __restrict__ hidden, const uint32_t* __restrict__ wfrag,
    const float* __restrict__ bias, const int* __restrict__ lenbuf,
    float* __restrict__ em) {
  const int blk = blockIdx.x;
  const int bb = blk >> 3, c = blk & 7;
  if (c * 64 >= lenbuf[bb]) return;
  const int tid = threadIdx.x;
  const int lane = tid & 63;
  const int w = tid >> 6;
  const int g = lane >> 4;
  const int li = lane & 15;
  const int row0 = blk * 64;
  __shared__ char lds_raw[64 * 128];

  floatx4 acc[4];
#pragma unroll
  for (int nt = 0; nt < 4; ++nt) acc[nt] = (floatx4)0.f;

  const float* hbase = hidden + (size_t)row0 * Hn;
  const short8* wf = (const short8*)wfrag;

  float4 pf[4];
#pragma unroll
  for (int k = 0; k < 4; ++k)
    pf[k] = *(const float4*)(hbase + (size_t)(w * 16 + 4 * k + g) * Hn + li * 4);

  for (int ch = 0; ch < Hn / BK; ++ch) {
#pragma unroll
    for (int k = 0; k < 4; ++k) {
      const int r = w * 16 + 4 * k + g;
      const uint32_t b0 = pack2(pf[k].x, pf[k].y);
      const uint32_t b1 = pack2(pf[k].z, pf[k].w);
      const int byteoff = r * 128 + ((li * 8) ^ ((r & 7) << 4));
      *(uint2*)(lds_raw + byteoff) = make_uint2(b0, b1);
    }
    if (ch + 1 < Hn / BK) {
      const int kc = (ch + 1) * BK;
#pragma unroll
      for (int k = 0; k < 4; ++k)
        pf[k] = *(const float4*)(hbase + (size_t)(w * 16 + 4 * k + g) * Hn + kc +
                                 li * 4);
    }
    asm volatile("s_waitcnt lgkmcnt(0)" ::: "memory");
#pragma unroll
    for (int ks = 0; ks < 2; ++ks) {
      const int r = w * 16 + li;
      const int kb = ks * 64 + g * 16;
      const short8 af =
          *(const short8*)(lds_raw + r * 128 + (kb ^ ((r & 7) << 4)));
      const int ksg = ch * 2 + ks;
#pragma unroll
      for (int nt = 0; nt < 4; ++nt) {
        const short8 bf = wf[(ksg * 4 + nt) * 64 + lane];
        acc[nt] =
            __builtin_amdgcn_mfma_f32_16x16x32_bf16(af, bf, acc[nt], 0, 0, 0);
      }
    }
  }
#pragma unroll
  for (int nt = 0; nt < 4; ++nt) {
    const int col = nt * 16 + li;
    if (col < Tn) {
      const float bs = bias[col];
#pragma unroll
      for (int r = 0; r < 4; ++r) {
        const int row = row0 + w * 16 + g * 4 + r;
        em[(size_t)row * Tn + col] = acc[nt][r] + bs;
      }
    }
  }
}

// ---------------- Kernel 2: chunked scans (f forward / g backward) ----------
// Block = 1 wave. blk -> (b, chunk c, dir). Chunk c covers t in [1+c*CH,
// min(1+(c+1)*CH, len)).  f: q <- exp(em_t) . (E^T q), init q0 (c==0) or 1.
// g: q <- E (exp(em_t) . q), t descending, init 1.  Renorm every 8 steps;
// final renorm; store normalized vector (+ log-scale for f; g's scale
// cancels in the stitch formula). f-blocks also emit chunk numerator partial.
__global__ __launch_bounds__(64) void scan_kernel(
    const float* __restrict__ em, const float* __restrict__ startT,
    const float* __restrict__ trans, const int* __restrict__ tag,
    const int* __restrict__ lenbuf, float* __restrict__ fvec,
    float* __restrict__ gvec, float* __restrict__ Lf,
    float* __restrict__ numpart) {
  const int blk = blockIdx.x;
  const int b = blk >> 5;              // NCH*2 = 32 tasks per batch
  const int c = (blk >> 1) & (NCH - 1);
  const int dir = blk & 1;             // 0 = forward (f), 1 = backward (g)
  const int len = lenbuf[b];
  const int t0 = 1 + c * CH;
  if (t0 >= len) return;
  if (dir && c == 0) return;  // g[0] never used
  const int t1 = (t0 + CH < len) ? t0 + CH : len;
  const int L = t1 - t0;
  const int lane = threadIdx.x;
  const int jc = lane < Tn ? lane : 0;
  const bool live = lane < Tn;
  const float* emb = em + (size_t)b * Sn * Tn;

  // ---- chunk numerator partial (f-blocks; lane = timestep) ----
  if (!dir) {
    float npv = 0.f;
    if (lane < L) {
      const int t = t0 + lane;
      const int tp = tag[b * Sn + t - 1], tc = tag[b * Sn + t];
      npv = trans[tp * Tn + tc] + emb[(size_t)t * Tn + tc];
    }
#pragma unroll
    for (int off = 1; off < 64; off <<= 1) npv += __shfl_xor(npv, off);
    if (lane == 0) numpart[b * NCH + c] = npv;
  }

  // ---- E fragment in VGPRs: column jc (f) or row jc (g) ----
  float e[Tn];
#pragma unroll
  for (int i = 0; i < Tn; ++i) {
    e[i] = __expf(dir ? trans[jc * Tn + i] : trans[i * Tn + jc]);
    asm volatile("" : "+v"(e[i]));  // pin in VGPR, block remat/spill
  }

  float Cacc = 0.f;
  float q;
  if (!dir)
    q = live ? (c == 0 ? __expf(startT[jc] + emb[jc]) : 1.f) : 0.f;
  else
    q = live ? 1.f : 0.f;

  // em prefetch pipeline over step index k (t = t0+k fwd, t1-1-k bwd)
#define T_OF(k) (dir ? (t1 - 1 - (k)) : (t0 + (k)))
  float ld1 = emb[(size_t)T_OF(0) * Tn + jc];
  const float ld2 = emb[(size_t)T_OF(L > 1 ? 1 : 0) * Tn + jc];
  float ee = live ? __expf(ld1) : 0.f;
  ld1 = ld2;

  for (int k = 0; k < L; ++k) {
    const float ee_cur = ee;
    const int kn = (k + 2 < L) ? k + 2 : L - 1;
    const float ldn = emb[(size_t)T_OF(kn) * Tn + jc];
    ee = live ? __expf(ld1) : 0.f;
    ld1 = ldn;

    const float x = dir ? ee_cur * q : q;  // g pre-multiplies by D_t
    float s0 = 0.f, s1 = 0.f, s2 = 0.f, s3 = 0.f;
#pragma unroll
    for (int i = 0; i < 48; i += 4) {
      s0 = fmaf(rdlane(x, i + 0), e[i + 0], s0);
      s1 = fmaf(rdlane(x, i + 1), e[i + 1], s1);
      s2 = fmaf(rdlane(x, i + 2), e[i + 2], s2);
      s3 = fmaf(rdlane(x, i + 3), e[i + 3], s3);
    }
    s0 = fmaf(rdlane(x, 48), e[48], s0);
    s1 = fmaf(rdlane(x, 49), e[49], s1);
    const float s = (s0 + s1) + (s2 + s3);
    q = dir ? s : ee_cur * s;  // f post-multiplies by D_t

    if ((k & 7) == 7) {
      float M = q;
#pragma unroll
      for (int off = 1; off < 64; off <<= 1) M = fmaxf(M, __shfl_xor(M, off));
      const float r = __builtin_amdgcn_rcpf(M);
      q *= r;
      Cacc -= __logf(r);
    }
  }
#undef T_OF

  // final renorm + store
  float M = q;
#pragma unroll
  for (int off = 1; off < 64; off <<= 1) M = fmaxf(M, __shfl_xor(M, off));
  const float r = __builtin_amdgcn_rcpf(M);
  const float qn = live ? q * r : 0.f;
  Cacc -= __logf(r);
  if (dir) {
    gvec[((size_t)b * NCH + c) * 64 + lane] = qn;
  } else {
    fvec[((size_t)b * NCH + c) * 64 + lane] = qn;
    if (lane == 0) Lf[b * NCH + c] = Cacc;
  }
}

// ---------------- Kernel 3: stitch — rank-1 chain + numerator ----------------
// den = Lf[C-1] + log(endv . f[C-1])
//     + sum_{c=1..C-1} ( Lf[c-1] + log(g[c] . f[c-1]) - log(sum g[c]) )
__global__ __launch_bounds__(64) void stitch_kernel(
    const float* __restrict__ em, const float* __restrict__ startT,
    const float* __restrict__ endT, const float* __restrict__ trans,
    const int* __restrict__ tag, const int* __restrict__ lenbuf,
    const float* __restrict__ fvec, const float* __restrict__ gvec,
    const float* __restrict__ Lf, const float* __restrict__ numpart,
    float* __restrict__ out) {
  const int b = blockIdx.x;
  const int lane = threadIdx.x;
  const int len = lenbuf[b];
  const int C = (len - 1 + CH - 1) / CH;
  const int jc = lane < Tn ? lane : 0;
  const bool live = lane < Tn;
  const float* emb = em + (size_t)b * Sn * Tn;

  // ---- numerator ----
  float np = (lane < C) ? numpart[b * NCH + lane] : 0.f;
#pragma unroll
  for (int off = 1; off < 64; off <<= 1) np += __shfl_xor(np, off);
  const int tg0 = tag[b * Sn];
  const int tgl = tag[b * Sn + len - 1];
  np += startT[tg0] + emb[tg0] + endT[tgl];

  // ---- denominator ----
  float den;
  if (C == 0) {  // len == 1
    float v = live ? (startT[jc] + emb[jc] + endT[jc]) : -INFINITY;
    float M = v;
#pragma unroll
    for (int off = 1; off < 64; off <<= 1) M = fmaxf(M, __shfl_xor(M, off));
    float s = __expf(v - M);
#pragma unroll
    for (int off = 1; off < 64; off <<= 1) s += __shfl_xor(s, off);
    den = M + __logf(s);
  } else {
    const float ev = live ? __expf(endT[jc]) : 0.f;
    float d = fvec[((size_t)b * NCH + C - 1) * 64 + lane] * ev;
#pragma unroll
    for (int off = 1; off < 64; off <<= 1) d += __shfl_xor(d, off);
    den = Lf[b * NCH + C - 1] + __logf(d);
    for (int c2 = 1; c2 < C; ++c2) {
      const float g = gvec[((size_t)b * NCH + c2) * 64 + lane];
      const float f = fvec[((size_t)b * NCH + c2 - 1) * 64 + lane];
      float dot = g * f;
      float gs = g;
#pragma unroll
      for (int off = 1; off < 64; off <<= 1) {
        dot += __shfl_xor(dot, off);
        gs += __shfl_xor(gs, off);
      }
      den += Lf[b * NCH + c2 - 1] + __logf(dot) - __logf(gs);
    }
  }
  if (lane == 0) out[b] = den - np;
}

extern "C" void kernel_launch(void* const* d_in, const int* in_sizes, int n_in,
                              void* d_out, int out_size, void* d_ws,
                              size_t ws_size, hipStream_t stream) {
  const float* hidden = (const float*)d_in[0];
  const float* W = (const float*)d_in[1];
  const float* bias = (const float*)d_in[2];
  const float* startT = (const float*)d_in[3];
  const float* endT = (const float*)d_in[4];
  const float* trans = (const float*)d_in[5];
  const int* tag = (const int*)d_in[6];
  const int* mask = (const int*)d_in[7];
  float* out = (float*)d_out;

  // ws layout
  char* ws = (char*)d_ws;
  float* em = (float*)ws;                                   // 6,553,600 B
  uint32_t* wfrag = (uint32_t*)(ws + 6553600);              //    98,304 B
  int* lenbuf = (int*)(ws + 6651904);                       //       256 B
  float* fvec = (float*)(ws + 6652160);                     //   262,144 B
  float* gvec = (float*)(ws + 6914304);                     //   262,144 B
  float* Lf = (float*)(ws + 7176448);                       //     4,096 B
  float* numpart = (float*)(ws + 7180544);                  //     4,096 B

  prep_kernel<<<88, 256, 0, stream>>>(W, mask, wfrag, lenbuf);
  emissions_kernel<<<(Bn * Sn) / 64, 256, 0, stream>>>(hidden, wfrag, bias,
                                                       lenbuf, em);
  scan_kernel<<<Bn * NCH * 2, 64, 0, stream>>>(em, startT, trans, tag, lenbuf,
                                               fvec, gvec, Lf, numpart);
  stitch_kernel<<<Bn, 64, 0, stream>>>(em, startT, endT, trans, tag, lenbuf,
                                       fvec, gvec, Lf, numpart, out);
}